// Round 2
// baseline (2311.073 us; speedup 1.0000x reference)
//
#include <hip/hip_runtime.h>
#include <math.h>

typedef unsigned short u16;
typedef unsigned int u32;

using short8 = __attribute__((ext_vector_type(8))) short;
using f32x4  = __attribute__((ext_vector_type(4))) float;
typedef _Float16 h2_t __attribute__((ext_vector_type(2)));

typedef const __attribute__((address_space(1))) unsigned int* gas_ptr;
typedef __attribute__((address_space(3))) unsigned int* las_ptr;

__device__ __forceinline__ void load_lds16(const void* g, void* l) {
    __builtin_amdgcn_global_load_lds((gas_ptr)g, (las_ptr)l, 16, 0, 0);
}

__device__ __forceinline__ u16 bf16b(float f) {
    u32 u = __builtin_bit_cast(u32, f);
    u += 0x7fffu + ((u >> 16) & 1u);
    return (u16)(u >> 16);
}
__device__ __forceinline__ float b2f(u16 h) {
    u32 u = (u32)h << 16;
    return __builtin_bit_cast(float, u);
}

// ---------------------------------------------------------------- convert fp32 -> bf16
__global__ void cvt_kernel(const float4* __restrict__ s, ushort4* __restrict__ d, int n4) {
    for (int i = blockIdx.x * blockDim.x + threadIdx.x; i < n4; i += gridDim.x * blockDim.x) {
        float4 v = s[i];
        ushort4 o;
        o.x = bf16b(v.x); o.y = bf16b(v.y); o.z = bf16b(v.z); o.w = bf16b(v.w);
        d[i] = o;
    }
}

// ---------------------------------------------------------------- generic bf16 GEMM
// C[M,N] = A[M,K] * B^T, B is [N,K] row-major. 128x128 tile, BK=64, 256 thr.
// MODE 0: out16[row*os + oc0 + col] = bf16(acc)                       (G1)
// MODE 1: out32[row*1024+col] = acc + addf[row*1024+col] + b2f(add16[row*1280+256+col])  (G2)
// MODE 2: out16[row*os+col] = bf16(gelu(acc + bias[col]))             (G3)
// MODE 3: out32[row*1024+col] = acc + bias[col] + b2f(add16[row*1024+col])               (G4)
template<int MODE>
__global__ __launch_bounds__(256) void gemm_bf16(
    const u16* __restrict__ Ab, const u16* __restrict__ Bb, int K, int ktiles,
    float* __restrict__ out32, u16* __restrict__ out16,
    const float* __restrict__ bias, const float* __restrict__ addf,
    const u16* __restrict__ add16, int out_stride, int out_col0)
{
    __shared__ __align__(16) u16 Als[128 * 64];
    __shared__ __align__(16) u16 Bls[128 * 64];

    const int tid  = threadIdx.x;
    const int lane = tid & 63;
    const int w    = tid >> 6;
    const int wr   = (w >> 1) * 64;
    const int wc   = (w & 1) * 64;
    const int fr   = lane & 15;
    const int fkB  = (lane >> 4) * 16;

    const size_t rb = (size_t)K * 2;
    const char* Ag = (const char*)Ab + ((size_t)blockIdx.y * 128 + (tid >> 3)) * rb + (size_t)(tid & 7) * 16;
    const char* Bg = (const char*)Bb + ((size_t)blockIdx.x * 128 + (tid >> 3)) * rb + (size_t)(tid & 7) * 16;
    char* Ald = (char*)Als + tid * 16;
    char* Bld = (char*)Bls + tid * 16;

    f32x4 acc[4][4];
#pragma unroll
    for (int m = 0; m < 4; ++m)
#pragma unroll
        for (int n = 0; n < 4; ++n)
            acc[m][n] = f32x4{0.f, 0.f, 0.f, 0.f};

    for (int kt = 0; kt < ktiles; ++kt) {
        __syncthreads();
        const char* Asrc = Ag + (size_t)kt * 128;
        const char* Bsrc = Bg + (size_t)kt * 128;
#pragma unroll
        for (int i = 0; i < 4; ++i) {
            load_lds16(Asrc + (size_t)(i * 32) * rb, Ald + i * 4096);
            load_lds16(Bsrc + (size_t)(i * 32) * rb, Bld + i * 4096);
        }
        __syncthreads();
#pragma unroll
        for (int kk = 0; kk < 2; ++kk) {
            short8 af[4], bfr[4];
#pragma unroll
            for (int m = 0; m < 4; ++m)
                af[m] = *(const short8*)((const char*)Als + (wr + m * 16 + fr) * 128 + kk * 64 + fkB);
#pragma unroll
            for (int n = 0; n < 4; ++n)
                bfr[n] = *(const short8*)((const char*)Bls + (wc + n * 16 + fr) * 128 + kk * 64 + fkB);
#pragma unroll
            for (int m = 0; m < 4; ++m)
#pragma unroll
                for (int n = 0; n < 4; ++n)
                    acc[m][n] = __builtin_amdgcn_mfma_f32_16x16x32_bf16(af[m], bfr[n], acc[m][n], 0, 0, 0);
        }
    }

    const int rbase = blockIdx.y * 128 + wr + (lane >> 4) * 4;
    const int cbase = blockIdx.x * 128 + wc + fr;
#pragma unroll
    for (int m = 0; m < 4; ++m) {
#pragma unroll
        for (int n = 0; n < 4; ++n) {
            const int col = cbase + n * 16;
#pragma unroll
            for (int r = 0; r < 4; ++r) {
                const int row = rbase + m * 16 + r;
                float v = acc[m][n][r];
                if (MODE == 0) {
                    out16[(size_t)row * out_stride + out_col0 + col] = bf16b(v);
                } else if (MODE == 1) {
                    out32[(size_t)row * 1024 + col] =
                        v + addf[(size_t)row * 1024 + col] + b2f(add16[(size_t)row * 1280 + 256 + col]);
                } else if (MODE == 2) {
                    float u = v + bias[col];
                    u = 0.5f * u * (1.0f + erff(u * 0.70710678118654752f));
                    out16[(size_t)row * out_stride + col] = bf16b(u);
                } else {
                    out32[(size_t)row * 1024 + col] =
                        v + bias[col] + b2f(add16[(size_t)row * 1024 + col]);
                }
            }
        }
    }
}

// ---------------------------------------------------------------- sequential scan
// 8 blocks (one per batch), 512 threads: thread (s=tid>>1, half=tid&1) owns
// A[s, half*128 .. +128] as 64 packed fp16 pairs in registers.
__global__ __launch_bounds__(512) void scan_kernel(
    const float* __restrict__ Am, const u16* __restrict__ xBb /*bf16, stride 1280*/,
    u16* __restrict__ states, float* __restrict__ fstate)
{
    __shared__ __align__(16) u32 stp[128];   // 256 fp16, packed
    const int tid  = threadIdx.x;
    const int b    = blockIdx.x;
    const int s    = tid >> 1;
    const int half = tid & 1;

    h2_t a[64];
    {
        const float4* ar = (const float4*)(Am + s * 256 + half * 128);
#pragma unroll
        for (int j = 0; j < 32; ++j) {
            float4 f = ar[j];
            a[2 * j]     = h2_t{(_Float16)f.x, (_Float16)f.y};
            a[2 * j + 1] = h2_t{(_Float16)f.z, (_Float16)f.w};
        }
    }
    if (tid < 128) stp[tid] = 0u;
    const u16* xrow = xBb + (size_t)b * 2048 * 1280 + s;
    u16* srow = states + (size_t)b * 2048 * 256 + s;

    float xb0 = b2f(xrow[0]);
    float xb1 = b2f(xrow[1280]);
    float xb2 = b2f(xrow[2 * 1280]);
    float xb3 = b2f(xrow[3 * 1280]);
    __syncthreads();

#define SCAN_STEP(T, XB, NEXT)                                                      \
    {                                                                               \
        float acc = 0.f;                                                            \
        const u32* sp = stp + half * 64;                                            \
        _Pragma("unroll")                                                           \
        for (int j = 0; j < 16; ++j) {                                              \
            uint4 sv = *(const uint4*)(sp + 4 * j);                                 \
            acc = __builtin_amdgcn_fdot2(a[4 * j + 0], __builtin_bit_cast(h2_t, sv.x), acc, false); \
            acc = __builtin_amdgcn_fdot2(a[4 * j + 1], __builtin_bit_cast(h2_t, sv.y), acc, false); \
            acc = __builtin_amdgcn_fdot2(a[4 * j + 2], __builtin_bit_cast(h2_t, sv.z), acc, false); \
            acc = __builtin_amdgcn_fdot2(a[4 * j + 3], __builtin_bit_cast(h2_t, sv.w), acc, false); \
        }                                                                           \
        float z = acc + __shfl_xor(acc, 1) + (XB);                                  \
        int tp = (T) + 4 <= 2047 ? (T) + 4 : 2047;                                  \
        (XB) = b2f(xrow[(size_t)tp * 1280]);                                        \
        float e = __expf(2.f * z);                                                  \
        float h = 1.f - 2.f / (e + 1.f);                                            \
        __syncthreads();                                                            \
        if (!half) {                                                                \
            reinterpret_cast<_Float16*>(stp)[s] = (_Float16)h;                      \
            srow[(size_t)(T) * 256] = bf16b(h);                                     \
            if ((T) == 2047) fstate[b * 256 + s] = h;                               \
        }                                                                           \
        __syncthreads();                                                            \
    }

    for (int t = 0; t < 2048; t += 4) {
        SCAN_STEP(t + 0, xb0, );
        SCAN_STEP(t + 1, xb1, );
        SCAN_STEP(t + 2, xb2, );
        SCAN_STEP(t + 3, xb3, );
    }
#undef SCAN_STEP
}

// ---------------------------------------------------------------- layernorm (row per block)
__global__ __launch_bounds__(256) void ln_kernel(
    const float* __restrict__ pre /*stride 1024*/, const float* __restrict__ gam,
    const float* __restrict__ bet, u16* __restrict__ ybf)
{
    const int row = blockIdx.x, tid = threadIdx.x;
    const float4 v = *(const float4*)(pre + (size_t)row * 1024 + tid * 4);
    float sum = v.x + v.y + v.z + v.w;
    float sq  = v.x * v.x + v.y * v.y + v.z * v.z + v.w * v.w;
#pragma unroll
    for (int o = 32; o; o >>= 1) { sum += __shfl_xor(sum, o); sq += __shfl_xor(sq, o); }
    __shared__ float red[8];
    const int lane = tid & 63, wv = tid >> 6;
    if (!lane) { red[wv] = sum; red[4 + wv] = sq; }
    __syncthreads();
    sum = red[0] + red[1] + red[2] + red[3];
    sq  = red[4] + red[5] + red[6] + red[7];
    const float mu  = sum * (1.f / 1024.f);
    const float var = sq * (1.f / 1024.f) - mu * mu;
    const float rs  = rsqrtf(var + 1e-5f);
    const float4 g  = *(const float4*)(gam + tid * 4);
    const float4 be = *(const float4*)(bet + tid * 4);
    ushort4 ob;
    ob.x = bf16b((v.x - mu) * rs * g.x + be.x);
    ob.y = bf16b((v.y - mu) * rs * g.y + be.y);
    ob.z = bf16b((v.z - mu) * rs * g.z + be.z);
    ob.w = bf16b((v.w - mu) * rs * g.w + be.w);
    *(ushort4*)(ybf + (size_t)row * 1024 + tid * 4) = ob;
}

// ---------------------------------------------------------------- launch
extern "C" void kernel_launch(void* const* d_in, const int* in_sizes, int n_in,
                              void* d_out, int out_size, void* d_ws, size_t ws_size,
                              hipStream_t stream)
{
    const float* x    = (const float*)d_in[0];
    const float* A    = (const float*)d_in[1];
    const float* Bm   = (const float*)d_in[2];
    const float* C    = (const float*)d_in[3];
    const float* D    = (const float*)d_in[4];
    const float* ln_w = (const float*)d_in[5];
    const float* ln_b = (const float*)d_in[6];
    const float* W1   = (const float*)d_in[7];
    const float* b1   = (const float*)d_in[8];
    const float* W2   = (const float*)d_in[9];
    const float* b2   = (const float*)d_in[10];

    // workspace layout (total 137,363,456 B)
    char* ws = (char*)d_ws;
    u16*   BmD    = (u16*)(ws + 0);            //  2,621,440 B (rows 0..255 Bm, 256..1279 D)
    u16*   C_bf   = (u16*)(ws + 2621440);      //    524,288 B
    u16*   W1b    = (u16*)(ws + 3145728);      //  8,388,608 B
    u16*   W2b    = (u16*)(ws + 11534336);     //  8,388,608 B
    u16*   xBD_bf = (u16*)(ws + 19922944);     // 41,943,040 B [16384 x 1280] bf16
    u16*   st_bf  = (u16*)(ws + 61865984);     //  8,388,608 B [16384 x 256] bf16
    u16*   y_bf   = (u16*)(ws + 70254592);     // 33,554,432 B [16384 x 1024] bf16
    u16*   h_bf   = (u16*)(ws + 103809024);    // 33,554,432 B [4096 x 4096] bf16 (chunk)

    float* out  = (float*)d_out;               // [16384*1024] y, then [2048] final_state
    u16*   x_bf = (u16*)d_out;                 // phase-1 scratch: bf16(x), dead after G1

    // convert inputs to bf16
    cvt_kernel<<<2048, 256, 0, stream>>>((const float4*)x,  (ushort4*)x_bf, 4194304);
    cvt_kernel<<<256,  256, 0, stream>>>((const float4*)Bm, (ushort4*)BmD, 65536);
    cvt_kernel<<<1024, 256, 0, stream>>>((const float4*)D,  (ushort4*)(BmD + 262144), 262144);
    cvt_kernel<<<256,  256, 0, stream>>>((const float4*)C,  (ushort4*)C_bf, 65536);
    cvt_kernel<<<2048, 256, 0, stream>>>((const float4*)W1, (ushort4*)W1b, 1048576);
    cvt_kernel<<<2048, 256, 0, stream>>>((const float4*)W2, (ushort4*)W2b, 1048576);

    dim3 blk(256);
    // G1: [16384,1024] x [1280,1024]^T -> xBD_bf (cols 0..255 = xB, 256..1279 = xD)
    gemm_bf16<0><<<dim3(10, 128), blk, 0, stream>>>(x_bf, BmD, 1024, 16,
        nullptr, xBD_bf, nullptr, nullptr, nullptr, 1280, 0);
    // sequential scan -> st_bf (bf16) + final_state (fp32 tail of d_out)
    scan_kernel<<<8, 512, 0, stream>>>(A, xBD_bf, st_bf, out + 16777216);
    // G2: states @ C^T + xD + x -> pre (fp32, into d_out; overwrites x_bf scratch)
    gemm_bf16<1><<<dim3(8, 128), blk, 0, stream>>>(st_bf, C_bf, 256, 4,
        out, nullptr, nullptr, x, xBD_bf, 1024, 0);
    // LN: pre (d_out) -> y_bf
    ln_kernel<<<16384, 256, 0, stream>>>(out, ln_w, ln_b, y_bf);
    // FFN in 4 row-chunks of 4096, reusing h_bf
    for (int c = 0; c < 4; ++c) {
        const u16* yc = y_bf + (size_t)c * 4096 * 1024;
        float* oc = out + (size_t)c * 4096 * 1024;
        gemm_bf16<2><<<dim3(32, 32), blk, 0, stream>>>(yc, W1b, 1024, 16,
            nullptr, h_bf, b1, nullptr, nullptr, 4096, 0);
        gemm_bf16<3><<<dim3(8, 32), blk, 0, stream>>>(h_bf, W2b, 4096, 64,
            oc, nullptr, b2, nullptr, yc, 1024, 0);
    }
}

// Round 3
// 2221.147 us; speedup vs baseline: 1.0405x; 1.0405x over previous
//
#include <hip/hip_runtime.h>
#include <math.h>

typedef unsigned short u16;
typedef unsigned int u32;

using short8 = __attribute__((ext_vector_type(8))) short;
using f32x4  = __attribute__((ext_vector_type(4))) float;
typedef _Float16 h2_t __attribute__((ext_vector_type(2)));

typedef const __attribute__((address_space(1))) unsigned int* gas_ptr;
typedef __attribute__((address_space(3))) unsigned int* las_ptr;

__device__ __forceinline__ void load_lds16(const void* g, void* l) {
    __builtin_amdgcn_global_load_lds((gas_ptr)g, (las_ptr)l, 16, 0, 0);
}

__device__ __forceinline__ u16 bf16b(float f) {
    u32 u = __builtin_bit_cast(u32, f);
    u += 0x7fffu + ((u >> 16) & 1u);
    return (u16)(u >> 16);
}
__device__ __forceinline__ float b2f(u16 h) {
    u32 u = (u32)h << 16;
    return __builtin_bit_cast(float, u);
}

// ---------------------------------------------------------------- fp32 -> bf16 (contig)
__global__ void cvt_kernel(const float4* __restrict__ s, ushort4* __restrict__ d, int n4) {
    for (int i = blockIdx.x * blockDim.x + threadIdx.x; i < n4; i += gridDim.x * blockDim.x) {
        float4 v = s[i];
        ushort4 o;
        o.x = bf16b(v.x); o.y = bf16b(v.y); o.z = bf16b(v.z); o.w = bf16b(v.w);
        d[i] = o;
    }
}
// fp32 [R,K] -> bf16 into dst[r*stride + col0 + k]
__global__ void cvt_str_kernel(const float4* __restrict__ s, u16* __restrict__ d,
                               int K4, int n4, int stride, int col0) {
    for (int i = blockIdx.x * blockDim.x + threadIdx.x; i < n4; i += gridDim.x * blockDim.x) {
        float4 v = s[i];
        int r = i / K4, k4 = (i - r * K4) * 4;
        ushort4 o;
        o.x = bf16b(v.x); o.y = bf16b(v.y); o.z = bf16b(v.z); o.w = bf16b(v.w);
        *(ushort4*)(d + (size_t)r * stride + col0 + k4) = o;
    }
}

// ---------------------------------------------------------------- generic bf16 GEMM
// C[M,N] = A[M,K] * B^T, B is [N,K] row-major. 128x128 tile, BK=64, 256 thr.
// MODE 0: out16[row*os+col] = bf16(acc)                               (G1: xB)
// MODE 1: split-A (st K=256 | x K=1024); out16 = bf16(acc + addf[row*1024+col])  (G2: pre-LN)
// MODE 2: out16[row*os+col] = bf16(gelu(acc + bias[col]))             (G3: FFN1)
// MODE 3: out32[row*1024+col] = acc + bias[col] + b2f(add16[row*1024+col])  (G4)
template<int MODE>
__global__ __launch_bounds__(256) void gemm_bf16(
    const u16* __restrict__ Ab, const u16* __restrict__ Ab2, const u16* __restrict__ Bb,
    int K, int ktiles,
    float* __restrict__ out32, u16* __restrict__ out16,
    const float* __restrict__ bias, const float* __restrict__ addf,
    const u16* __restrict__ add16, int out_stride)
{
    __shared__ __align__(16) u16 Als[128 * 64];
    __shared__ __align__(16) u16 Bls[128 * 64];

    const int tid  = threadIdx.x;
    const int lane = tid & 63;
    const int w    = tid >> 6;
    const int wr   = (w >> 1) * 64;
    const int wc   = (w & 1) * 64;
    const int fr   = lane & 15;
    const int fkB  = (lane >> 4) * 16;

    const size_t rbB = (size_t)K * 2;
    const int arow = blockIdx.y * 128 + (tid >> 3);
    const char* Ag  = (const char*)Ab + (size_t)arow * ((MODE == 1) ? 512 : rbB) + (size_t)(tid & 7) * 16;
    const char* Ag2 = (MODE == 1) ? ((const char*)Ab2 + (size_t)arow * 2048 + (size_t)(tid & 7) * 16) : nullptr;
    const char* Bg  = (const char*)Bb + ((size_t)blockIdx.x * 128 + (tid >> 3)) * rbB + (size_t)(tid & 7) * 16;
    char* Ald = (char*)Als + tid * 16;
    char* Bld = (char*)Bls + tid * 16;

    f32x4 acc[4][4];
#pragma unroll
    for (int m = 0; m < 4; ++m)
#pragma unroll
        for (int n = 0; n < 4; ++n)
            acc[m][n] = f32x4{0.f, 0.f, 0.f, 0.f};

    for (int kt = 0; kt < ktiles; ++kt) {
        __syncthreads();
        const char* Asrc;
        size_t rbA;
        if (MODE == 1) {
            if (kt < 4) { Asrc = Ag  + (size_t)kt * 128;       rbA = 512;  }
            else        { Asrc = Ag2 + (size_t)(kt - 4) * 128; rbA = 2048; }
        } else {
            Asrc = Ag + (size_t)kt * 128; rbA = rbB;
        }
        const char* Bsrc = Bg + (size_t)kt * 128;
#pragma unroll
        for (int i = 0; i < 4; ++i) {
            load_lds16(Asrc + (size_t)(i * 32) * rbA, Ald + i * 4096);
            load_lds16(Bsrc + (size_t)(i * 32) * rbB, Bld + i * 4096);
        }
        __syncthreads();
#pragma unroll
        for (int kk = 0; kk < 2; ++kk) {
            short8 af[4], bfr[4];
#pragma unroll
            for (int m = 0; m < 4; ++m)
                af[m] = *(const short8*)((const char*)Als + (wr + m * 16 + fr) * 128 + kk * 64 + fkB);
#pragma unroll
            for (int n = 0; n < 4; ++n)
                bfr[n] = *(const short8*)((const char*)Bls + (wc + n * 16 + fr) * 128 + kk * 64 + fkB);
#pragma unroll
            for (int m = 0; m < 4; ++m)
#pragma unroll
                for (int n = 0; n < 4; ++n)
                    acc[m][n] = __builtin_amdgcn_mfma_f32_16x16x32_bf16(af[m], bfr[n], acc[m][n], 0, 0, 0);
        }
    }

    const int rbase = blockIdx.y * 128 + wr + (lane >> 4) * 4;
    const int cbase = blockIdx.x * 128 + wc + fr;
#pragma unroll
    for (int m = 0; m < 4; ++m) {
#pragma unroll
        for (int n = 0; n < 4; ++n) {
            const int col = cbase + n * 16;
#pragma unroll
            for (int r = 0; r < 4; ++r) {
                const int row = rbase + m * 16 + r;
                float v = acc[m][n][r];
                if (MODE == 0) {
                    out16[(size_t)row * out_stride + col] = bf16b(v);
                } else if (MODE == 1) {
                    out16[(size_t)row * 1024 + col] = bf16b(v + addf[(size_t)row * 1024 + col]);
                } else if (MODE == 2) {
                    float u = v + bias[col];
                    u = 0.5f * u * (1.0f + erff(u * 0.70710678118654752f));
                    out16[(size_t)row * out_stride + col] = bf16b(u);
                } else {
                    out32[(size_t)row * 1024 + col] =
                        v + bias[col] + b2f(add16[(size_t)row * 1024 + col]);
                }
            }
        }
    }
}

// ---------------------------------------------------------------- sequential scan
// 8 blocks (one per batch), 1024 threads: thread (s=tid>>2, q=tid&3) owns
// A[s, q*64 .. +64] as 32 packed fp16 pairs in registers.
// State double-buffered in LDS, padded so the 4 per-read addresses hit
// disjoint banks: quarter q lives at u32 offset q*36 (byte q*144).
__global__ __launch_bounds__(1024) void scan_kernel(
    const float* __restrict__ Am, const u16* __restrict__ xBb /*bf16, stride 256*/,
    u16* __restrict__ states, float* __restrict__ fstate)
{
    __shared__ __align__(16) u32 SB[2][144];
    const int tid = threadIdx.x;
    const int b   = blockIdx.x;
    const int s   = tid >> 2;
    const int q   = tid & 3;

    h2_t a[32];
    {
        const float4* ar = (const float4*)(Am + s * 256 + q * 64);
#pragma unroll
        for (int j = 0; j < 16; ++j) {
            float4 f = ar[j];
            a[2 * j]     = h2_t{(_Float16)f.x, (_Float16)f.y};
            a[2 * j + 1] = h2_t{(_Float16)f.z, (_Float16)f.w};
        }
    }
    if (tid < 144) SB[0][tid] = 0u;

    const u16* xrow = xBb + (size_t)b * 2048 * 256 + s;
    u16* srow = states + (size_t)b * 2048 * 256 + s;
    const int widx = (s >> 6) * 72 + (s & 63);   // u16 slot of state elem s

    float xb0 = b2f(xrow[0]);
    float xb1 = b2f(xrow[256]);
    float xb2 = b2f(xrow[512]);
    float xb3 = b2f(xrow[768]);
    __syncthreads();

#define SCAN_STEP(T, XB)                                                            \
    {                                                                               \
        const u32* sp = SB[(T) & 1] + q * 36;                                       \
        float ac0 = 0.f, ac1 = 0.f, ac2 = 0.f, ac3 = 0.f;                           \
        _Pragma("unroll")                                                           \
        for (int j = 0; j < 8; ++j) {                                               \
            uint4 sv = *(const uint4*)(sp + 4 * j);                                 \
            ac0 = __builtin_amdgcn_fdot2(a[4 * j + 0], __builtin_bit_cast(h2_t, sv.x), ac0, false); \
            ac1 = __builtin_amdgcn_fdot2(a[4 * j + 1], __builtin_bit_cast(h2_t, sv.y), ac1, false); \
            ac2 = __builtin_amdgcn_fdot2(a[4 * j + 2], __builtin_bit_cast(h2_t, sv.z), ac2, false); \
            ac3 = __builtin_amdgcn_fdot2(a[4 * j + 3], __builtin_bit_cast(h2_t, sv.w), ac3, false); \
        }                                                                           \
        float zq = (ac0 + ac1) + (ac2 + ac3);                                       \
        zq += __shfl_xor(zq, 1);                                                    \
        float z = zq + __shfl_xor(zq, 2) + (XB);                                    \
        int tp = (T) + 4 <= 2047 ? (T) + 4 : 2047;                                  \
        (XB) = b2f(xrow[(size_t)tp * 256]);                                        \
        float e = __expf(2.f * z);                                                  \
        float h = 1.f - 2.f / (e + 1.f);                                            \
        if (!q) {                                                                   \
            reinterpret_cast<_Float16*>(SB[((T) + 1) & 1])[widx] = (_Float16)h;     \
            srow[(size_t)(T) * 256] = bf16b(h);                                     \
            if ((T) == 2047) fstate[b * 256 + s] = h;                               \
        }                                                                           \
        __syncthreads();                                                            \
    }

    for (int t = 0; t < 2048; t += 4) {
        SCAN_STEP(t + 0, xb0);
        SCAN_STEP(t + 1, xb1);
        SCAN_STEP(t + 2, xb2);
        SCAN_STEP(t + 3, xb3);
    }
#undef SCAN_STEP
}

// ---------------------------------------------------------------- layernorm (row per block, bf16 in)
__global__ __launch_bounds__(256) void ln_kernel(
    const u16* __restrict__ pre /*bf16, stride 1024*/, const float* __restrict__ gam,
    const float* __restrict__ bet, u16* __restrict__ ybf)
{
    const int row = blockIdx.x, tid = threadIdx.x;
    const ushort4 pv = *(const ushort4*)(pre + (size_t)row * 1024 + tid * 4);
    float vx = b2f(pv.x), vy = b2f(pv.y), vz = b2f(pv.z), vw = b2f(pv.w);
    float sum = vx + vy + vz + vw;
    float sq  = vx * vx + vy * vy + vz * vz + vw * vw;
#pragma unroll
    for (int o = 32; o; o >>= 1) { sum += __shfl_xor(sum, o); sq += __shfl_xor(sq, o); }
    __shared__ float red[8];
    const int lane = tid & 63, wv = tid >> 6;
    if (!lane) { red[wv] = sum; red[4 + wv] = sq; }
    __syncthreads();
    sum = red[0] + red[1] + red[2] + red[3];
    sq  = red[4] + red[5] + red[6] + red[7];
    const float mu  = sum * (1.f / 1024.f);
    const float var = sq * (1.f / 1024.f) - mu * mu;
    const float rs  = rsqrtf(var + 1e-5f);
    const float4 g  = *(const float4*)(gam + tid * 4);
    const float4 be = *(const float4*)(bet + tid * 4);
    ushort4 ob;
    ob.x = bf16b((vx - mu) * rs * g.x + be.x);
    ob.y = bf16b((vy - mu) * rs * g.y + be.y);
    ob.z = bf16b((vz - mu) * rs * g.z + be.z);
    ob.w = bf16b((vw - mu) * rs * g.w + be.w);
    *(ushort4*)(ybf + (size_t)row * 1024 + tid * 4) = ob;
}

// ---------------------------------------------------------------- launch
extern "C" void kernel_launch(void* const* d_in, const int* in_sizes, int n_in,
                              void* d_out, int out_size, void* d_ws, size_t ws_size,
                              hipStream_t stream)
{
    const float* x    = (const float*)d_in[0];
    const float* A    = (const float*)d_in[1];
    const float* Bm   = (const float*)d_in[2];
    const float* C    = (const float*)d_in[3];
    const float* D    = (const float*)d_in[4];
    const float* ln_w = (const float*)d_in[5];
    const float* ln_b = (const float*)d_in[6];
    const float* W1   = (const float*)d_in[7];
    const float* b1   = (const float*)d_in[8];
    const float* W2   = (const float*)d_in[9];
    const float* b2   = (const float*)d_in[10];

    // workspace layout (total 135,790,592 B)
    char* ws = (char*)d_ws;
    u16* Bm_bf  = (u16*)(ws + 0);            //    524,288 B [256 x 1024]
    u16* CD_bf  = (u16*)(ws + 524288);       //  2,621,440 B [1024 x 1280] = C|D
    u16* W1b    = (u16*)(ws + 3145728);      //  8,388,608 B
    u16* W2b    = (u16*)(ws + 11534336);     //  8,388,608 B
    u16* xB_bf  = (u16*)(ws + 19922944);     //  8,388,608 B [16384 x 256]
    u16* st_bf  = (u16*)(ws + 28311552);     //  8,388,608 B [16384 x 256]
    u16* y_bf   = (u16*)(ws + 36700160);     // 33,554,432 B [16384 x 1024]
    u16* pre_bf = (u16*)(ws + 70254592);     // 33,554,432 B [16384 x 1024]
    u16* xh_bf  = (u16*)(ws + 103809024);    // 33,554,432 B shared: x_bf (phase 1-2) / h_bf (FFN)

    float* out = (float*)d_out;              // [16384*1024] y, then [2048] final_state

    // convert inputs to bf16
    cvt_kernel<<<2048, 256, 0, stream>>>((const float4*)x,  (ushort4*)xh_bf, 4194304);
    cvt_kernel<<<256,  256, 0, stream>>>((const float4*)Bm, (ushort4*)Bm_bf, 65536);
    cvt_str_kernel<<<256,  256, 0, stream>>>((const float4*)C, CD_bf, 64, 65536, 1280, 0);
    cvt_str_kernel<<<1024, 256, 0, stream>>>((const float4*)D, CD_bf, 256, 262144, 1280, 256);
    cvt_kernel<<<2048, 256, 0, stream>>>((const float4*)W1, (ushort4*)W1b, 1048576);
    cvt_kernel<<<2048, 256, 0, stream>>>((const float4*)W2, (ushort4*)W2b, 1048576);

    dim3 blk(256);
    // G1: xB = x @ Bm^T -> bf16 [16384,256]
    gemm_bf16<0><<<dim3(2, 128), blk, 0, stream>>>(xh_bf, nullptr, Bm_bf, 1024, 16,
        nullptr, xB_bf, nullptr, nullptr, nullptr, 256);
    // scan -> st_bf + final_state
    scan_kernel<<<8, 1024, 0, stream>>>(A, xB_bf, st_bf, out + 16777216);
    // G2: [st | x] @ [C | D]^T + x -> pre_bf (K=1280)
    gemm_bf16<1><<<dim3(8, 128), blk, 0, stream>>>(st_bf, xh_bf, CD_bf, 1280, 20,
        nullptr, pre_bf, nullptr, x, nullptr, 1024);
    // LN
    ln_kernel<<<16384, 256, 0, stream>>>(pre_bf, ln_w, ln_b, y_bf);
    // FFN in 4 row-chunks of 4096 (h reuses xh_bf; x_bf dead after G2)
    for (int c = 0; c < 4; ++c) {
        const u16* yc = y_bf + (size_t)c * 4096 * 1024;
        float* oc = out + (size_t)c * 4096 * 1024;
        gemm_bf16<2><<<dim3(32, 32), blk, 0, stream>>>(yc, nullptr, W1b, 1024, 16,
            nullptr, xh_bf, b1, nullptr, nullptr, 4096);
        gemm_bf16<3><<<dim3(8, 32), blk, 0, stream>>>(xh_bf, nullptr, W2b, 4096, 64,
            oc, nullptr, b2, nullptr, yc, 1024);
    }
}

// Round 4
// 1853.148 us; speedup vs baseline: 1.2471x; 1.1986x over previous
//
#include <hip/hip_runtime.h>
#include <math.h>

typedef unsigned short u16;
typedef unsigned int u32;

using short8 = __attribute__((ext_vector_type(8))) short;
using f32x4  = __attribute__((ext_vector_type(4))) float;
typedef _Float16 h2_t __attribute__((ext_vector_type(2)));

typedef const __attribute__((address_space(1))) unsigned int* gas_ptr;
typedef __attribute__((address_space(3))) unsigned int* las_ptr;

__device__ __forceinline__ void load_lds16(const void* g, void* l) {
    __builtin_amdgcn_global_load_lds((gas_ptr)g, (las_ptr)l, 16, 0, 0);
}

__device__ __forceinline__ u16 bf16b(float f) {
    u32 u = __builtin_bit_cast(u32, f);
    u += 0x7fffu + ((u >> 16) & 1u);
    return (u16)(u >> 16);
}
__device__ __forceinline__ float b2f(u16 h) {
    u32 u = (u32)h << 16;
    return __builtin_bit_cast(float, u);
}

// v + (v moved by DPP ctrl) — pure VALU cross-lane add
template<int CTRL>
__device__ __forceinline__ float dpp_add(float v) {
    int m = __builtin_amdgcn_update_dpp(0, __builtin_bit_cast(int, v), CTRL, 0xF, 0xF, true);
    return v + __builtin_bit_cast(float, m);
}

// ---------------------------------------------------------------- fp32 -> bf16 (contig)
__global__ void cvt_kernel(const float4* __restrict__ s, ushort4* __restrict__ d, int n4) {
    for (int i = blockIdx.x * blockDim.x + threadIdx.x; i < n4; i += gridDim.x * blockDim.x) {
        float4 v = s[i];
        ushort4 o;
        o.x = bf16b(v.x); o.y = bf16b(v.y); o.z = bf16b(v.z); o.w = bf16b(v.w);
        d[i] = o;
    }
}
// fp32 [R,K] -> bf16 into dst[r*stride + col0 + k]
__global__ void cvt_str_kernel(const float4* __restrict__ s, u16* __restrict__ d,
                               int K4, int n4, int stride, int col0) {
    for (int i = blockIdx.x * blockDim.x + threadIdx.x; i < n4; i += gridDim.x * blockDim.x) {
        float4 v = s[i];
        int r = i / K4, k4 = (i - r * K4) * 4;
        ushort4 o;
        o.x = bf16b(v.x); o.y = bf16b(v.y); o.z = bf16b(v.z); o.w = bf16b(v.w);
        *(ushort4*)(d + (size_t)r * stride + col0 + k4) = o;
    }
}

// ---------------------------------------------------------------- generic bf16 GEMM
// C[M,N] = A[M,K] * B^T, B is [N,K] row-major. 128x128 tile, BK=64, 256 thr.
template<int MODE>
__global__ __launch_bounds__(256) void gemm_bf16(
    const u16* __restrict__ Ab, const u16* __restrict__ Ab2, const u16* __restrict__ Bb,
    int K, int ktiles,
    float* __restrict__ out32, u16* __restrict__ out16,
    const float* __restrict__ bias, const float* __restrict__ addf,
    const u16* __restrict__ add16, int out_stride)
{
    __shared__ __align__(16) u16 Als[128 * 64];
    __shared__ __align__(16) u16 Bls[128 * 64];

    const int tid  = threadIdx.x;
    const int lane = tid & 63;
    const int w    = tid >> 6;
    const int wr   = (w >> 1) * 64;
    const int wc   = (w & 1) * 64;
    const int fr   = lane & 15;
    const int fkB  = (lane >> 4) * 16;

    const size_t rbB = (size_t)K * 2;
    const int arow = blockIdx.y * 128 + (tid >> 3);
    const char* Ag  = (const char*)Ab + (size_t)arow * ((MODE == 1) ? 512 : rbB) + (size_t)(tid & 7) * 16;
    const char* Ag2 = (MODE == 1) ? ((const char*)Ab2 + (size_t)arow * 2048 + (size_t)(tid & 7) * 16) : nullptr;
    const char* Bg  = (const char*)Bb + ((size_t)blockIdx.x * 128 + (tid >> 3)) * rbB + (size_t)(tid & 7) * 16;
    char* Ald = (char*)Als + tid * 16;
    char* Bld = (char*)Bls + tid * 16;

    f32x4 acc[4][4];
#pragma unroll
    for (int m = 0; m < 4; ++m)
#pragma unroll
        for (int n = 0; n < 4; ++n)
            acc[m][n] = f32x4{0.f, 0.f, 0.f, 0.f};

    for (int kt = 0; kt < ktiles; ++kt) {
        __syncthreads();
        const char* Asrc;
        size_t rbA;
        if (MODE == 1) {
            if (kt < 4) { Asrc = Ag  + (size_t)kt * 128;       rbA = 512;  }
            else        { Asrc = Ag2 + (size_t)(kt - 4) * 128; rbA = 2048; }
        } else {
            Asrc = Ag + (size_t)kt * 128; rbA = rbB;
        }
        const char* Bsrc = Bg + (size_t)kt * 128;
#pragma unroll
        for (int i = 0; i < 4; ++i) {
            load_lds16(Asrc + (size_t)(i * 32) * rbA, Ald + i * 4096);
            load_lds16(Bsrc + (size_t)(i * 32) * rbB, Bld + i * 4096);
        }
        __syncthreads();
#pragma unroll
        for (int kk = 0; kk < 2; ++kk) {
            short8 af[4], bfr[4];
#pragma unroll
            for (int m = 0; m < 4; ++m)
                af[m] = *(const short8*)((const char*)Als + (wr + m * 16 + fr) * 128 + kk * 64 + fkB);
#pragma unroll
            for (int n = 0; n < 4; ++n)
                bfr[n] = *(const short8*)((const char*)Bls + (wc + n * 16 + fr) * 128 + kk * 64 + fkB);
#pragma unroll
            for (int m = 0; m < 4; ++m)
#pragma unroll
                for (int n = 0; n < 4; ++n)
                    acc[m][n] = __builtin_amdgcn_mfma_f32_16x16x32_bf16(af[m], bfr[n], acc[m][n], 0, 0, 0);
        }
    }

    const int rbase = blockIdx.y * 128 + wr + (lane >> 4) * 4;
    const int cbase = blockIdx.x * 128 + wc + fr;
#pragma unroll
    for (int m = 0; m < 4; ++m) {
#pragma unroll
        for (int n = 0; n < 4; ++n) {
            const int col = cbase + n * 16;
#pragma unroll
            for (int r = 0; r < 4; ++r) {
                const int row = rbase + m * 16 + r;
                float v = acc[m][n][r];
                if (MODE == 0) {
                    out16[(size_t)row * out_stride + col] = bf16b(v);
                } else if (MODE == 1) {
                    out16[(size_t)row * 1024 + col] = bf16b(v + addf[(size_t)row * 1024 + col]);
                } else if (MODE == 2) {
                    float u = v + bias[col];
                    u = 0.5f * u * (1.0f + erff(u * 0.70710678118654752f));
                    out16[(size_t)row * out_stride + col] = bf16b(u);
                } else {
                    out32[(size_t)row * 1024 + col] =
                        v + bias[col] + b2f(add16[(size_t)row * 1024 + col]);
                }
            }
        }
    }
}

// ---------------------------------------------------------------- sequential scan
// 8 blocks (one per batch), 512 threads = 8 waves.
// Thread (g = tid>>3, q = tid&7): owns A[4g..4g+4][32q..32q+32) as h2 regs.
// State double-buffered in LDS, chunk q at byte offset q*80 (bank-disjoint).
// Cross-k reduce via DPP butterfly (pure VALU). Lane q<4 finalizes row 4g+(q&3).
__global__ __launch_bounds__(512) void scan_kernel(
    const float* __restrict__ Am, const u16* __restrict__ xBb /*bf16, [b][t][256]*/,
    u16* __restrict__ states, float* __restrict__ fstate)
{
    __shared__ __align__(16) u32 SB[2][160];   // 2 x 640 B (8 chunks x 80 B)
    const int tid = threadIdx.x;
    const int b   = blockIdx.x;
    const int g   = tid >> 3;
    const int q   = tid & 7;
    const int lq  = q & 3;

    h2_t a[4][16];
#pragma unroll
    for (int r = 0; r < 4; ++r) {
        const float4* ar = (const float4*)(Am + (size_t)(4 * g + r) * 256 + 32 * q);
#pragma unroll
        for (int jj = 0; jj < 8; ++jj) {
            float4 f = ar[jj];
            a[r][2 * jj]     = h2_t{(_Float16)f.x, (_Float16)f.y};
            a[r][2 * jj + 1] = h2_t{(_Float16)f.z, (_Float16)f.w};
        }
    }
    if (tid < 160) SB[0][tid] = 0u;

    const int srw = 4 * g + lq;                          // state row this lane finalizes
    const u16* xrow = xBb + (size_t)b * 2048 * 256 + 4 * g;
    u16* srow = states + (size_t)b * 2048 * 256 + srw;
    const int lbyte = (srw >> 5) * 80 + (srw & 31) * 2;  // byte offset within buffer
    const bool wlane = (q < 4);
    _Float16* sb0 = (_Float16*)((char*)&SB[0][0] + lbyte);
    _Float16* sb1 = (_Float16*)((char*)&SB[1][0] + lbyte);

    uint2 xp0 = *(const uint2*)(xrow);
    uint2 xp1 = *(const uint2*)(xrow + 256);
    uint2 xp2 = *(const uint2*)(xrow + 512);
    uint2 xp3 = *(const uint2*)(xrow + 768);
    __syncthreads();

#define ROW_DOT(ZR, R, W0, W1, W2, W3)                                               \
    ZR = __builtin_amdgcn_fdot2(a[R][0],  __builtin_bit_cast(h2_t, W0.x), ZR, false); \
    ZR = __builtin_amdgcn_fdot2(a[R][1],  __builtin_bit_cast(h2_t, W0.y), ZR, false); \
    ZR = __builtin_amdgcn_fdot2(a[R][2],  __builtin_bit_cast(h2_t, W0.z), ZR, false); \
    ZR = __builtin_amdgcn_fdot2(a[R][3],  __builtin_bit_cast(h2_t, W0.w), ZR, false); \
    ZR = __builtin_amdgcn_fdot2(a[R][4],  __builtin_bit_cast(h2_t, W1.x), ZR, false); \
    ZR = __builtin_amdgcn_fdot2(a[R][5],  __builtin_bit_cast(h2_t, W1.y), ZR, false); \
    ZR = __builtin_amdgcn_fdot2(a[R][6],  __builtin_bit_cast(h2_t, W1.z), ZR, false); \
    ZR = __builtin_amdgcn_fdot2(a[R][7],  __builtin_bit_cast(h2_t, W1.w), ZR, false); \
    ZR = __builtin_amdgcn_fdot2(a[R][8],  __builtin_bit_cast(h2_t, W2.x), ZR, false); \
    ZR = __builtin_amdgcn_fdot2(a[R][9],  __builtin_bit_cast(h2_t, W2.y), ZR, false); \
    ZR = __builtin_amdgcn_fdot2(a[R][10], __builtin_bit_cast(h2_t, W2.z), ZR, false); \
    ZR = __builtin_amdgcn_fdot2(a[R][11], __builtin_bit_cast(h2_t, W2.w), ZR, false); \
    ZR = __builtin_amdgcn_fdot2(a[R][12], __builtin_bit_cast(h2_t, W3.x), ZR, false); \
    ZR = __builtin_amdgcn_fdot2(a[R][13], __builtin_bit_cast(h2_t, W3.y), ZR, false); \
    ZR = __builtin_amdgcn_fdot2(a[R][14], __builtin_bit_cast(h2_t, W3.z), ZR, false); \
    ZR = __builtin_amdgcn_fdot2(a[R][15], __builtin_bit_cast(h2_t, W3.w), ZR, false);

#define SCAN_STEP(T, XP)                                                             \
    {                                                                                \
        const u32* sp = &SB[(T) & 1][q * 20];                                        \
        uint4 s0 = *(const uint4*)(sp + 0);                                          \
        uint4 s1 = *(const uint4*)(sp + 4);                                          \
        uint4 s2 = *(const uint4*)(sp + 8);                                          \
        uint4 s3 = *(const uint4*)(sp + 12);                                         \
        float z0 = 0.f, z1 = 0.f, z2 = 0.f, z3 = 0.f;                                \
        ROW_DOT(z0, 0, s0, s1, s2, s3)                                               \
        ROW_DOT(z1, 1, s0, s1, s2, s3)                                               \
        ROW_DOT(z2, 2, s0, s1, s2, s3)                                               \
        ROW_DOT(z3, 3, s0, s1, s2, s3)                                               \
        z0 = dpp_add<0xB1>(z0);  z1 = dpp_add<0xB1>(z1);                             \
        z2 = dpp_add<0xB1>(z2);  z3 = dpp_add<0xB1>(z3);                             \
        z0 = dpp_add<0x4E>(z0);  z1 = dpp_add<0x4E>(z1);                             \
        z2 = dpp_add<0x4E>(z2);  z3 = dpp_add<0x4E>(z3);                             \
        z0 = dpp_add<0x141>(z0); z1 = dpp_add<0x141>(z1);                            \
        z2 = dpp_add<0x141>(z2); z3 = dpp_add<0x141>(z3);                            \
        float t0 = (lq & 1) ? z1 : z0;                                               \
        float t1 = (lq & 1) ? z3 : z2;                                               \
        float zm = (lq & 2) ? t1 : t0;                                               \
        u32 wsel = (lq & 2) ? XP.y : XP.x;                                           \
        u32 hsel = (lq & 1) ? (wsel >> 16) : (wsel & 0xFFFFu);                       \
        zm += b2f((u16)hsel);                                                        \
        int tp = (T) + 4 <= 2047 ? (T) + 4 : 2047;                                   \
        XP = *(const uint2*)(xrow + (size_t)tp * 256);                               \
        float e = __expf(2.f * zm);                                                  \
        float h = 1.f - 2.f * __builtin_amdgcn_rcpf(e + 1.f);                        \
        if (wlane) {                                                                 \
            *((((T) + 1) & 1) ? sb1 : sb0) = (_Float16)h;                            \
            srow[(size_t)(T) * 256] = bf16b(h);                                      \
            if ((T) == 2047) fstate[b * 256 + srw] = h;                              \
        }                                                                            \
        __syncthreads();                                                             \
    }

    for (int t = 0; t < 2048; t += 4) {
        SCAN_STEP(t + 0, xp0);
        SCAN_STEP(t + 1, xp1);
        SCAN_STEP(t + 2, xp2);
        SCAN_STEP(t + 3, xp3);
    }
#undef SCAN_STEP
#undef ROW_DOT
}

// ---------------------------------------------------------------- layernorm (row per block, bf16 in)
__global__ __launch_bounds__(256) void ln_kernel(
    const u16* __restrict__ pre /*bf16, stride 1024*/, const float* __restrict__ gam,
    const float* __restrict__ bet, u16* __restrict__ ybf)
{
    const int row = blockIdx.x, tid = threadIdx.x;
    const ushort4 pv = *(const ushort4*)(pre + (size_t)row * 1024 + tid * 4);
    float vx = b2f(pv.x), vy = b2f(pv.y), vz = b2f(pv.z), vw = b2f(pv.w);
    float sum = vx + vy + vz + vw;
    float sq  = vx * vx + vy * vy + vz * vz + vw * vw;
#pragma unroll
    for (int o = 32; o; o >>= 1) { sum += __shfl_xor(sum, o); sq += __shfl_xor(sq, o); }
    __shared__ float red[8];
    const int lane = tid & 63, wv = tid >> 6;
    if (!lane) { red[wv] = sum; red[4 + wv] = sq; }
    __syncthreads();
    sum = red[0] + red[1] + red[2] + red[3];
    sq  = red[4] + red[5] + red[6] + red[7];
    const float mu  = sum * (1.f / 1024.f);
    const float var = sq * (1.f / 1024.f) - mu * mu;
    const float rs  = rsqrtf(var + 1e-5f);
    const float4 g  = *(const float4*)(gam + tid * 4);
    const float4 be = *(const float4*)(bet + tid * 4);
    ushort4 ob;
    ob.x = bf16b((vx - mu) * rs * g.x + be.x);
    ob.y = bf16b((vy - mu) * rs * g.y + be.y);
    ob.z = bf16b((vz - mu) * rs * g.z + be.z);
    ob.w = bf16b((vw - mu) * rs * g.w + be.w);
    *(ushort4*)(ybf + (size_t)row * 1024 + tid * 4) = ob;
}

// ---------------------------------------------------------------- launch
extern "C" void kernel_launch(void* const* d_in, const int* in_sizes, int n_in,
                              void* d_out, int out_size, void* d_ws, size_t ws_size,
                              hipStream_t stream)
{
    const float* x    = (const float*)d_in[0];
    const float* A    = (const float*)d_in[1];
    const float* Bm   = (const float*)d_in[2];
    const float* C    = (const float*)d_in[3];
    const float* D    = (const float*)d_in[4];
    const float* ln_w = (const float*)d_in[5];
    const float* ln_b = (const float*)d_in[6];
    const float* W1   = (const float*)d_in[7];
    const float* b1   = (const float*)d_in[8];
    const float* W2   = (const float*)d_in[9];
    const float* b2   = (const float*)d_in[10];

    // workspace layout (total 135,790,592 B)
    char* ws = (char*)d_ws;
    u16* Bm_bf  = (u16*)(ws + 0);            //    524,288 B [256 x 1024]
    u16* CD_bf  = (u16*)(ws + 524288);       //  2,621,440 B [1024 x 1280] = C|D
    u16* W1b    = (u16*)(ws + 3145728);      //  8,388,608 B
    u16* W2b    = (u16*)(ws + 11534336);     //  8,388,608 B
    u16* xB_bf  = (u16*)(ws + 19922944);     //  8,388,608 B [16384 x 256]
    u16* st_bf  = (u16*)(ws + 28311552);     //  8,388,608 B [16384 x 256]
    u16* y_bf   = (u16*)(ws + 36700160);     // 33,554,432 B [16384 x 1024]
    u16* pre_bf = (u16*)(ws + 70254592);     // 33,554,432 B [16384 x 1024]
    u16* xh_bf  = (u16*)(ws + 103809024);    // 33,554,432 B shared: x_bf / h_bf

    float* out = (float*)d_out;              // [16384*1024] y, then [2048] final_state

    cvt_kernel<<<2048, 256, 0, stream>>>((const float4*)x,  (ushort4*)xh_bf, 4194304);
    cvt_kernel<<<256,  256, 0, stream>>>((const float4*)Bm, (ushort4*)Bm_bf, 65536);
    cvt_str_kernel<<<256,  256, 0, stream>>>((const float4*)C, CD_bf, 64, 65536, 1280, 0);
    cvt_str_kernel<<<1024, 256, 0, stream>>>((const float4*)D, CD_bf, 256, 262144, 1280, 256);
    cvt_kernel<<<2048, 256, 0, stream>>>((const float4*)W1, (ushort4*)W1b, 1048576);
    cvt_kernel<<<2048, 256, 0, stream>>>((const float4*)W2, (ushort4*)W2b, 1048576);

    dim3 blk(256);
    // G1: xB = x @ Bm^T -> bf16 [16384,256]
    gemm_bf16<0><<<dim3(2, 128), blk, 0, stream>>>(xh_bf, nullptr, Bm_bf, 1024, 16,
        nullptr, xB_bf, nullptr, nullptr, nullptr, 256);
    // scan -> st_bf + final_state
    scan_kernel<<<8, 512, 0, stream>>>(A, xB_bf, st_bf, out + 16777216);
    // G2: [st | x] @ [C | D]^T + x -> pre_bf (K=1280)
    gemm_bf16<1><<<dim3(8, 128), blk, 0, stream>>>(st_bf, xh_bf, CD_bf, 1280, 20,
        nullptr, pre_bf, nullptr, x, nullptr, 1024);
    // LN
    ln_kernel<<<16384, 256, 0, stream>>>(pre_bf, ln_w, ln_b, y_bf);
    // FFN in 4 row-chunks of 4096 (h reuses xh_bf; x_bf dead after G2)
    for (int c = 0; c < 4; ++c) {
        const u16* yc = y_bf + (size_t)c * 4096 * 1024;
        float* oc = out + (size_t)c * 4096 * 1024;
        gemm_bf16<2><<<dim3(32, 32), blk, 0, stream>>>(yc, nullptr, W1b, 1024, 16,
            nullptr, xh_bf, b1, nullptr, nullptr, 4096);
        gemm_bf16<3><<<dim3(8, 32), blk, 0, stream>>>(xh_bf, nullptr, W2b, 4096, 64,
            oc, nullptr, b2, nullptr, yc, 1024);
    }
}